// Round 5
// baseline (335.567 us; speedup 1.0000x reference)
//
#include <hip/hip_runtime.h>
#include <stdint.h>

typedef _Float16 f16x8 __attribute__((ext_vector_type(8)));
typedef float floatx4 __attribute__((ext_vector_type(4)));

#define RR 147456   // 384*384 rows
#define NC 128      // channels
#define NN 384

__device__ inline floatx4 zero4() { floatx4 v; v[0]=0.f; v[1]=0.f; v[2]=0.f; v[3]=0.f; return v; }
__device__ inline float sigmoidf_(float x) { return 1.f / (1.f + __expf(-x)); }

// ---------------------------------------------------------------------------
// k0: repack six fp32 128x128 weights into fp16 FRAGMENT-MAJOR order:
//   wf[slot][ ((k0*8 + nt)*64 + lane)*8 + j ] = W[k][n]
//   where k = k0*32 + (lane>>4)*8 + j,  n = nt*16 + (lane&15)
// A lane's MFMA B-operand for (k0,nt) is ONE coalesced 16B load.
// slots: 0=Wa 1=Wga 2=Wb 3=Wgb 4=Wg 5=Wo. L2-resident afterwards.
// ---------------------------------------------------------------------------
__global__ __launch_bounds__(256) void k0_wt(
    const float* __restrict__ w0, const float* __restrict__ w1,
    const float* __restrict__ w2, const float* __restrict__ w3,
    const float* __restrict__ w4, const float* __restrict__ w5,
    _Float16* __restrict__ wf)
{
  const float* w;
  switch (blockIdx.x) {
    case 0: w = w0; break; case 1: w = w1; break; case 2: w = w2; break;
    case 3: w = w3; break; case 4: w = w4; break; default: w = w5; break;
  }
  _Float16* out = wf + blockIdx.x * 16384;
  const int t = threadIdx.x;
  for (int it = 0; it < 64; ++it) {
    int f = it * 256 + t;
    int j  = f & 7;
    int ln = (f >> 3) & 63;
    int nt = (f >> 9) & 7;
    int k0 = f >> 12;
    int k = k0 * 32 + (ln >> 4) * 8 + j;
    int n = nt * 16 + (ln & 15);
    out[f] = (_Float16)w[k * 128 + n];
  }
}

// ---------------------------------------------------------------------------
// k2: per 64-row tile: LN1 -> zn fp16 in LDS -> ONE barrier -> 5 GEMMs.
// N-split: wave w owns channel-tiles {2w,2w+1}: block reads each weight byte
// exactly once. REGISTER-LEAN schedule (target <=128 total regs incl. acc):
//   - A-fragments reloaded from LDS per mt (not cached across GEMMs)
//   - G-GEMM first -> sigmoid packed to fp16 (16 regs) -> P-GEMM reuses acc
//   - single bw[4][2] weight buffer, one-slot-ahead load placement
// ---------------------------------------------------------------------------
__global__ __launch_bounds__(256, 4) void k2_ln_gemm(
    const float* __restrict__ z, const float* __restrict__ ln1g, const float* __restrict__ ln1b,
    const _Float16* __restrict__ wf,
    const float* __restrict__ ba, const float* __restrict__ bga,
    const float* __restrict__ bb, const float* __restrict__ bgb,
    const float* __restrict__ bg,
    _Float16* __restrict__ at, _Float16* __restrict__ bt, _Float16* __restrict__ gate)
{
  __shared__ __align__(16) _Float16 zns[64][136];   // zn tile, padded stride
  const int t = threadIdx.x;
  const int w = t >> 6, lane = t & 63;
  const int l15 = lane & 15, quad = lane >> 4;
  const int r0 = blockIdx.x * 64;
  const int nt0 = w * 2;            // this wave's channel-tile pair

  // ---- LN1: wave w owns rows w*16..w*16+15 (16-lane-group reduce)
  {
    const int g = lane >> 4, h = lane & 15;
    float4 ga = *(const float4*)(ln1g + h*8);
    float4 gb = *(const float4*)(ln1g + h*8 + 4);
    float4 bba = *(const float4*)(ln1b + h*8);
    float4 bbb = *(const float4*)(ln1b + h*8 + 4);
    #pragma unroll
    for (int rr = 0; rr < 4; ++rr) {
      int row = w * 16 + rr * 4 + g;
      const float* zp = z + (size_t)(r0 + row) * NC + h * 8;
      float4 xa = *(const float4*)zp;
      float4 xb = *(const float4*)(zp + 4);
      float s = xa.x + xa.y + xa.z + xa.w + xb.x + xb.y + xb.z + xb.w;
      float q = xa.x*xa.x + xa.y*xa.y + xa.z*xa.z + xa.w*xa.w
              + xb.x*xb.x + xb.y*xb.y + xb.z*xb.z + xb.w*xb.w;
      #pragma unroll
      for (int m = 1; m < 16; m <<= 1) { s += __shfl_xor(s, m); q += __shfl_xor(q, m); }
      float mean = s * (1.f/128.f);
      float var  = q * (1.f/128.f) - mean*mean;
      float rs = rsqrtf(var + 1e-5f);
      union { uint4 u; _Float16 hh[8]; } pk;
      pk.hh[0] = (_Float16)((xa.x - mean) * rs * ga.x + bba.x);
      pk.hh[1] = (_Float16)((xa.y - mean) * rs * ga.y + bba.y);
      pk.hh[2] = (_Float16)((xa.z - mean) * rs * ga.z + bba.z);
      pk.hh[3] = (_Float16)((xa.w - mean) * rs * ga.w + bba.w);
      pk.hh[4] = (_Float16)((xb.x - mean) * rs * gb.x + bbb.x);
      pk.hh[5] = (_Float16)((xb.y - mean) * rs * gb.y + bbb.y);
      pk.hh[6] = (_Float16)((xb.z - mean) * rs * gb.z + bbb.z);
      pk.hh[7] = (_Float16)((xb.w - mean) * rs * gb.w + bbb.w);
      *(uint4*)&zns[row][h * 8] = pk.u;
    }
  }
  __syncthreads();

  const _Float16* pw = wf + lane * 8;
  f16x8 bw[4][2];                   // single weight buffer (32 regs)
  floatx4 acc[4][2];                // single accumulator set (32 regs)
  union PkU { unsigned int u; _Float16 h[2]; };
  PkU sig[4][2][2];                 // packed sigmoid results (16 regs)

  auto loadw = [&](int slot) {
    const _Float16* p = pw + slot * 16384;
    #pragma unroll
    for (int k0 = 0; k0 < 4; ++k0)
      #pragma unroll
      for (int j = 0; j < 2; ++j)
        bw[k0][j] = *(const f16x8*)(p + (k0*8 + nt0 + j) * 512);
  };
  auto dogemm = [&]() {
    #pragma unroll
    for (int mt = 0; mt < 4; ++mt) {
      acc[mt][0] = zero4(); acc[mt][1] = zero4();
      #pragma unroll
      for (int k0 = 0; k0 < 4; ++k0) {
        f16x8 af = *(const f16x8*)&zns[mt*16 + l15][k0*32 + quad*8];
        acc[mt][0] = __builtin_amdgcn_mfma_f32_16x16x32_f16(af, bw[k0][0], acc[mt][0], 0, 0, 0);
        acc[mt][1] = __builtin_amdgcn_mfma_f32_16x16x32_f16(af, bw[k0][1], acc[mt][1], 0, 0, 0);
      }
    }
  };
  auto sigpack = [&](const float* big) {
    #pragma unroll
    for (int j = 0; j < 2; ++j) {
      float bgv = big[(nt0 + j)*16 + l15];
      #pragma unroll
      for (int mt = 0; mt < 4; ++mt) {
        sig[mt][j][0].h[0] = (_Float16)sigmoidf_(acc[mt][j][0] + bgv);
        sig[mt][j][0].h[1] = (_Float16)sigmoidf_(acc[mt][j][1] + bgv);
        sig[mt][j][1].h[0] = (_Float16)sigmoidf_(acc[mt][j][2] + bgv);
        sig[mt][j][1].h[1] = (_Float16)sigmoidf_(acc[mt][j][3] + bgv);
      }
    }
  };
  auto combine_store = [&](const float* bia, _Float16* dst) {
    #pragma unroll
    for (int j = 0; j < 2; ++j) {
      int c = (nt0 + j)*16 + l15;
      float bav = bia[c];
      #pragma unroll
      for (int mt = 0; mt < 4; ++mt) {
        union { uint2 u2; _Float16 h[4]; } pk;
        pk.h[0] = (_Float16)((acc[mt][j][0] + bav) * (float)sig[mt][j][0].h[0]);
        pk.h[1] = (_Float16)((acc[mt][j][1] + bav) * (float)sig[mt][j][0].h[1]);
        pk.h[2] = (_Float16)((acc[mt][j][2] + bav) * (float)sig[mt][j][1].h[0]);
        pk.h[3] = (_Float16)((acc[mt][j][3] + bav) * (float)sig[mt][j][1].h[1]);
        *(uint2*)(dst + (size_t)c * RR + r0 + mt*16 + quad*4) = pk.u2;
      }
    }
  };

  // pair 1: Wga (gate) then Wa (proj) -> at
  loadw(1); dogemm(); sigpack(bga);
  loadw(0); dogemm();
  loadw(3);                          // prefetch Wgb (bw free after last dogemm consumed it)
  combine_store(ba, at);
  // pair 2: Wgb then Wb -> bt
  dogemm(); sigpack(bgb);
  loadw(2); dogemm();
  loadw(4);                          // prefetch Wg
  combine_store(bb, bt);
  // gate: Wg
  dogemm();
  #pragma unroll
  for (int j = 0; j < 2; ++j) {
    int c = (nt0 + j)*16 + l15;
    float bgv = bg[c];
    #pragma unroll
    for (int mt = 0; mt < 4; ++mt) {
      union { uint2 u2; _Float16 h[4]; } pk;
      #pragma unroll
      for (int r = 0; r < 4; ++r)
        pk.h[r] = (_Float16)sigmoidf_(acc[mt][j][r] + bgv);
      *(uint2*)(gate + (size_t)c * RR + r0 + mt*16 + quad*4) = pk.u2;
    }
  }
}

// ---------------------------------------------------------------------------
// k3: triangle einsum. Per channel c: o_t[c] = A_c(384x384) @ B_c^T.
// grid (9 tiles, 128 channels); block computes 128x128 o-tile, wave = 64x64.
// Output now fp16 (halves write traffic; LN2 tolerates 5e-4 rel error).
// ---------------------------------------------------------------------------
__global__ __launch_bounds__(256) void k3_tri(
    const _Float16* __restrict__ at, const _Float16* __restrict__ bt, _Float16* __restrict__ o)
{
  __shared__ __align__(16) _Float16 As[128][72];
  __shared__ __align__(16) _Float16 Bs[128][72];
  const int t = threadIdx.x;
  const int w = t >> 6, lane = t & 63, l15 = lane & 15, quad = lane >> 4;
  const int c = blockIdx.y;
  const int i0 = (blockIdx.x / 3) * 128, j0 = (blockIdx.x % 3) * 128;
  const int wi = w >> 1, wj = w & 1;
  const size_t base = (size_t)c * RR;
  const _Float16* A  = at + base;
  const _Float16* Bp = bt + base;

  floatx4 acc[4][4];
  #pragma unroll
  for (int mt = 0; mt < 4; ++mt)
    #pragma unroll
    for (int nt = 0; nt < 4; ++nt) acc[mt][nt] = zero4();

  for (int kk = 0; kk < NN; kk += 64) {
    #pragma unroll
    for (int s2 = 0; s2 < 4; ++s2) {
      int f = s2 * 2048 + t * 8;        // contiguous across lanes
      int row = f >> 6, k = f & 63;
      *(uint4*)&As[row][k] = *(const uint4*)(A  + (size_t)(i0 + row) * NN + kk + k);
      *(uint4*)&Bs[row][k] = *(const uint4*)(Bp + (size_t)(j0 + row) * NN + kk + k);
    }
    __syncthreads();
    #pragma unroll
    for (int k0 = 0; k0 < 64; k0 += 32) {
      f16x8 af[4], bfr[4];
      #pragma unroll
      for (int mt = 0; mt < 4; ++mt) af[mt]  = *(const f16x8*)&As[wi*64 + mt*16 + l15][k0 + quad*8];
      #pragma unroll
      for (int nt = 0; nt < 4; ++nt) bfr[nt] = *(const f16x8*)&Bs[wj*64 + nt*16 + l15][k0 + quad*8];
      #pragma unroll
      for (int mt = 0; mt < 4; ++mt)
        #pragma unroll
        for (int nt = 0; nt < 4; ++nt)
          acc[mt][nt] = __builtin_amdgcn_mfma_f32_16x16x32_f16(af[mt], bfr[nt], acc[mt][nt], 0, 0, 0);
    }
    __syncthreads();
  }
  // store fp16, 32B-contiguous per (quad,reg) row
  #pragma unroll
  for (int mt = 0; mt < 4; ++mt) {
    #pragma unroll
    for (int r = 0; r < 4; ++r) {
      int i = i0 + wi*64 + mt*16 + quad*4 + r;
      _Float16* orow = o + base + (size_t)i * NN + j0 + wj*64;
      #pragma unroll
      for (int nt = 0; nt < 4; ++nt) orow[nt*16 + l15] = (_Float16)acc[mt][nt][r];
    }
  }
}

// ---------------------------------------------------------------------------
// k4: per 64-position tile: gather o16 (channel-major fp16) -> LDS transpose
//     -> LN2 IN PLACE (each lane owns its 8 columns) -> N-split MFMA with Wo
//     from L2 -> *gate -> fp32 out.  Single 17KB LDS buffer.
// ---------------------------------------------------------------------------
__global__ __launch_bounds__(256, 4) void k4_out(
    const _Float16* __restrict__ o, const _Float16* __restrict__ gate,
    const float* __restrict__ ln2g, const float* __restrict__ ln2b,
    const _Float16* __restrict__ wo5, const float* __restrict__ bo,
    float* __restrict__ out)
{
  __shared__ __align__(16) _Float16 osb[64][136];   // o tile [pos][c]; LN2 in place
  const int t = threadIdx.x;
  const int w = t >> 6, lane = t & 63, l15 = lane & 15, quad = lane >> 4;
  const int r0 = blockIdx.x * 64;
  const int nt0 = w * 2;

  // gather o16: 16B per lane per channel plane, transpose into [pos][c]
  #pragma unroll
  for (int it = 0; it < 4; ++it) {
    int f = (it * 256 + t) * 8;
    int cx = f >> 6, p = f & 63;
    f16x8 v = *(const f16x8*)(o + (size_t)cx * RR + r0 + p);
    #pragma unroll
    for (int i = 0; i < 8; ++i) osb[p + i][cx] = v[i];
  }
  __syncthreads();

  // LN2 in place: lane (g = lane>>4, h = lane&15) owns cols h*8..h*8+7 of its rows
  {
    const int g = lane >> 4, h = lane & 15;
    float4 ga = *(const float4*)(ln2g + h*8);
    float4 gb = *(const float4*)(ln2g + h*8 + 4);
    float4 bba = *(const float4*)(ln2b + h*8);
    float4 bbb = *(const float4*)(ln2b + h*8 + 4);
    #pragma unroll
    for (int rr = 0; rr < 4; ++rr) {
      int row = w * 16 + rr * 4 + g;
      f16x8 xv = *(const f16x8*)&osb[row][h*8];
      float x0 = (float)xv[0], x1 = (float)xv[1], x2 = (float)xv[2], x3 = (float)xv[3];
      float x4 = (float)xv[4], x5 = (float)xv[5], x6 = (float)xv[6], x7 = (float)xv[7];
      float s = x0+x1+x2+x3+x4+x5+x6+x7;
      float q = x0*x0+x1*x1+x2*x2+x3*x3+x4*x4+x5*x5+x6*x6+x7*x7;
      #pragma unroll
      for (int m = 1; m < 16; m <<= 1) { s += __shfl_xor(s, m); q += __shfl_xor(q, m); }
      float mean = s * (1.f/128.f);
      float var  = q * (1.f/128.f) - mean*mean;
      float rs = rsqrtf(var + 1e-5f);
      union { uint4 u; _Float16 hh[8]; } pk;
      pk.hh[0] = (_Float16)((x0 - mean) * rs * ga.x + bba.x);
      pk.hh[1] = (_Float16)((x1 - mean) * rs * ga.y + bba.y);
      pk.hh[2] = (_Float16)((x2 - mean) * rs * ga.z + bba.z);
      pk.hh[3] = (_Float16)((x3 - mean) * rs * ga.w + bba.w);
      pk.hh[4] = (_Float16)((x4 - mean) * rs * gb.x + bbb.x);
      pk.hh[5] = (_Float16)((x5 - mean) * rs * gb.y + bbb.y);
      pk.hh[6] = (_Float16)((x6 - mean) * rs * gb.z + bbb.z);
      pk.hh[7] = (_Float16)((x7 - mean) * rs * gb.w + bbb.w);
      *(uint4*)&osb[row][h * 8] = pk.u;
    }
  }
  __syncthreads();

  // N-split GEMM: wave owns channel-tiles {2w,2w+1}; Wo streamed from L2
  f16x8 bw[4][2];
  {
    const _Float16* p = wo5 + lane * 8;
    #pragma unroll
    for (int k0 = 0; k0 < 4; ++k0)
      #pragma unroll
      for (int j = 0; j < 2; ++j)
        bw[k0][j] = *(const f16x8*)(p + (k0*8 + nt0 + j) * 512);
  }
  floatx4 acc[4][2];
  #pragma unroll
  for (int mt = 0; mt < 4; ++mt) {
    acc[mt][0] = zero4(); acc[mt][1] = zero4();
    #pragma unroll
    for (int k0 = 0; k0 < 4; ++k0) {
      f16x8 af = *(const f16x8*)&osb[mt*16 + l15][k0*32 + quad*8];
      acc[mt][0] = __builtin_amdgcn_mfma_f32_16x16x32_f16(af, bw[k0][0], acc[mt][0], 0, 0, 0);
      acc[mt][1] = __builtin_amdgcn_mfma_f32_16x16x32_f16(af, bw[k0][1], acc[mt][1], 0, 0, 0);
    }
  }

  // epilogue: out = gate * (acc + bo); gate channel-major fp16, 8B loads
  #pragma unroll
  for (int j = 0; j < 2; ++j) {
    int c = (nt0 + j)*16 + l15;
    float bov = bo[c];
    #pragma unroll
    for (int mt = 0; mt < 4; ++mt) {
      union { uint2 u2; _Float16 h[4]; } gk;
      gk.u2 = *(const uint2*)(gate + (size_t)c * RR + r0 + mt*16 + quad*4);
      #pragma unroll
      for (int r = 0; r < 4; ++r) {
        int rl = mt*16 + quad*4 + r;
        out[(size_t)(r0 + rl) * NC + c] = (float)gk.h[r] * (acc[mt][j][r] + bov);
      }
    }
  }
}

// ---------------------------------------------------------------------------
// Workspace layout (bytes):
//   a_t   @ 0          : 147456*128*2 = 37748736   (fp16, channel-major)
//   b_t   @ 37748736   : 37748736
//   gate  @ 75497472   : 37748736                  (fp16, channel-major)
//   o16   @ 113246208  : 147456*128*2 = 37748736   (fp16, channel-major)
//   wf    @ 188743680  : 6*16384*2 = 196608        (fragment-major fp16 weights)
//   total 188940288
// ---------------------------------------------------------------------------
extern "C" void kernel_launch(void* const* d_in, const int* in_sizes, int n_in,
                              void* d_out, int out_size, void* d_ws, size_t ws_size,
                              hipStream_t stream) {
  const float* z    = (const float*)d_in[0];
  const float* l1g  = (const float*)d_in[1];
  const float* l1b  = (const float*)d_in[2];
  const float* l2g  = (const float*)d_in[3];
  const float* l2b  = (const float*)d_in[4];
  const float* Wa   = (const float*)d_in[5];
  const float* ba   = (const float*)d_in[6];
  const float* Wga  = (const float*)d_in[7];
  const float* bga  = (const float*)d_in[8];
  const float* Wb   = (const float*)d_in[9];
  const float* bb   = (const float*)d_in[10];
  const float* Wgb  = (const float*)d_in[11];
  const float* bgb  = (const float*)d_in[12];
  const float* Wg   = (const float*)d_in[13];
  const float* bg   = (const float*)d_in[14];
  const float* Wo   = (const float*)d_in[15];
  const float* bo   = (const float*)d_in[16];

  char* ws = (char*)d_ws;
  _Float16* at_  = (_Float16*)(ws + 0);
  _Float16* bt_  = (_Float16*)(ws + 37748736);
  _Float16* gate = (_Float16*)(ws + 75497472);
  _Float16* o16  = (_Float16*)(ws + 113246208);
  _Float16* wf   = (_Float16*)(ws + 188743680);

  hipLaunchKernelGGL(k0_wt, dim3(6), dim3(256), 0, stream, Wa, Wga, Wb, Wgb, Wg, Wo, wf);
  hipLaunchKernelGGL(k2_ln_gemm, dim3(2304), dim3(256), 0, stream,
                     z, l1g, l1b, wf, ba, bga, bb, bgb, bg, at_, bt_, gate);
  hipLaunchKernelGGL(k3_tri, dim3(9, 128), dim3(256), 0, stream, at_, bt_, o16);
  hipLaunchKernelGGL(k4_out, dim3(2304), dim3(256), 0, stream,
                     o16, gate, l2g, l2b, wf + 5*16384, bo, (float*)d_out);
}

// Round 6
// 329.056 us; speedup vs baseline: 1.0198x; 1.0198x over previous
//
#include <hip/hip_runtime.h>
#include <stdint.h>

typedef _Float16 f16x8 __attribute__((ext_vector_type(8)));
typedef float floatx4 __attribute__((ext_vector_type(4)));

#define RR 147456   // 384*384 rows
#define NC 128      // channels
#define NN 384

__device__ inline floatx4 zero4() { floatx4 v; v[0]=0.f; v[1]=0.f; v[2]=0.f; v[3]=0.f; return v; }
__device__ inline float sigmoidf_(float x) { return 1.f / (1.f + __expf(-x)); }

// ---------------------------------------------------------------------------
// k0: repack six fp32 128x128 weights into fp16 FRAGMENT-MAJOR order:
//   wf[slot][ ((k0*8 + nt)*64 + lane)*8 + j ] = W[k][n]
//   where k = k0*32 + (lane>>4)*8 + j,  n = nt*16 + (lane&15)
// A lane's MFMA B-operand for (k0,nt) is ONE coalesced 16B load.
// slots: 0=Wa 1=Wga 2=Wb 3=Wgb 4=Wg 5=Wo. L2-resident afterwards.
// ---------------------------------------------------------------------------
__global__ __launch_bounds__(256) void k0_wt(
    const float* __restrict__ w0, const float* __restrict__ w1,
    const float* __restrict__ w2, const float* __restrict__ w3,
    const float* __restrict__ w4, const float* __restrict__ w5,
    _Float16* __restrict__ wf)
{
  const float* w;
  switch (blockIdx.x) {
    case 0: w = w0; break; case 1: w = w1; break; case 2: w = w2; break;
    case 3: w = w3; break; case 4: w = w4; break; default: w = w5; break;
  }
  _Float16* out = wf + blockIdx.x * 16384;
  const int t = threadIdx.x;
  for (int it = 0; it < 64; ++it) {
    int f = it * 256 + t;
    int j  = f & 7;
    int ln = (f >> 3) & 63;
    int nt = (f >> 9) & 7;
    int k0 = f >> 12;
    int k = k0 * 32 + (ln >> 4) * 8 + j;
    int n = nt * 16 + (ln & 15);
    out[f] = (_Float16)w[k * 128 + n];
  }
}

// ---------------------------------------------------------------------------
// k2: per 64-row tile: LN1 -> zn fp16 in LDS -> ONE barrier -> 5 GEMMs.
// N-split: wave w owns channel-tiles {2w,2w+1}. Register-lean (round-5).
// NEW: outputs bounce through a per-wave LDS tile so global stores are
// 16B/lane with each 4-lane group writing one FULL 64B line per instruction
// (kills the partial-line RFO/write-amplification seen in round-5 counters).
// ---------------------------------------------------------------------------
__global__ __launch_bounds__(256, 4) void k2_ln_gemm(
    const float* __restrict__ z, const float* __restrict__ ln1g, const float* __restrict__ ln1b,
    const _Float16* __restrict__ wf,
    const float* __restrict__ ba, const float* __restrict__ bga,
    const float* __restrict__ bb, const float* __restrict__ bgb,
    const float* __restrict__ bg,
    _Float16* __restrict__ at, _Float16* __restrict__ bt, _Float16* __restrict__ gate)
{
  __shared__ __align__(16) _Float16 zns[64][136];    // zn tile, padded stride
  __shared__ __align__(16) _Float16 bnc[4][32 * 72]; // per-wave store bounce [c'][row], stride 72
  const int t = threadIdx.x;
  const int w = t >> 6, lane = t & 63;
  const int l15 = lane & 15, quad = lane >> 4;
  const int r0 = blockIdx.x * 64;
  const int nt0 = w * 2;            // this wave's channel-tile pair

  // ---- LN1: wave w owns rows w*16..w*16+15 (16-lane-group reduce)
  {
    const int g = lane >> 4, h = lane & 15;
    float4 ga = *(const float4*)(ln1g + h*8);
    float4 gb = *(const float4*)(ln1g + h*8 + 4);
    float4 bba = *(const float4*)(ln1b + h*8);
    float4 bbb = *(const float4*)(ln1b + h*8 + 4);
    #pragma unroll
    for (int rr = 0; rr < 4; ++rr) {
      int row = w * 16 + rr * 4 + g;
      const float* zp = z + (size_t)(r0 + row) * NC + h * 8;
      float4 xa = *(const float4*)zp;
      float4 xb = *(const float4*)(zp + 4);
      float s = xa.x + xa.y + xa.z + xa.w + xb.x + xb.y + xb.z + xb.w;
      float q = xa.x*xa.x + xa.y*xa.y + xa.z*xa.z + xa.w*xa.w
              + xb.x*xb.x + xb.y*xb.y + xb.z*xb.z + xb.w*xb.w;
      #pragma unroll
      for (int m = 1; m < 16; m <<= 1) { s += __shfl_xor(s, m); q += __shfl_xor(q, m); }
      float mean = s * (1.f/128.f);
      float var  = q * (1.f/128.f) - mean*mean;
      float rs = rsqrtf(var + 1e-5f);
      union { uint4 u; _Float16 hh[8]; } pk;
      pk.hh[0] = (_Float16)((xa.x - mean) * rs * ga.x + bba.x);
      pk.hh[1] = (_Float16)((xa.y - mean) * rs * ga.y + bba.y);
      pk.hh[2] = (_Float16)((xa.z - mean) * rs * ga.z + bba.z);
      pk.hh[3] = (_Float16)((xa.w - mean) * rs * ga.w + bba.w);
      pk.hh[4] = (_Float16)((xb.x - mean) * rs * gb.x + bbb.x);
      pk.hh[5] = (_Float16)((xb.y - mean) * rs * gb.y + bbb.y);
      pk.hh[6] = (_Float16)((xb.z - mean) * rs * gb.z + bbb.z);
      pk.hh[7] = (_Float16)((xb.w - mean) * rs * gb.w + bbb.w);
      *(uint4*)&zns[row][h * 8] = pk.u;
    }
  }
  __syncthreads();

  const _Float16* pw = wf + lane * 8;
  f16x8 bw[4][2];                   // single weight buffer
  floatx4 acc[4][2];                // single accumulator set
  union PkU { unsigned int u; _Float16 h[2]; };
  PkU sig[4][2][2];                 // packed sigmoid results

  auto loadw = [&](int slot) {
    const _Float16* p = pw + slot * 16384;
    #pragma unroll
    for (int k0 = 0; k0 < 4; ++k0)
      #pragma unroll
      for (int j = 0; j < 2; ++j)
        bw[k0][j] = *(const f16x8*)(p + (k0*8 + nt0 + j) * 512);
  };
  auto dogemm = [&]() {
    #pragma unroll
    for (int mt = 0; mt < 4; ++mt) {
      acc[mt][0] = zero4(); acc[mt][1] = zero4();
      #pragma unroll
      for (int k0 = 0; k0 < 4; ++k0) {
        f16x8 af = *(const f16x8*)&zns[mt*16 + l15][k0*32 + quad*8];
        acc[mt][0] = __builtin_amdgcn_mfma_f32_16x16x32_f16(af, bw[k0][0], acc[mt][0], 0, 0, 0);
        acc[mt][1] = __builtin_amdgcn_mfma_f32_16x16x32_f16(af, bw[k0][1], acc[mt][1], 0, 0, 0);
      }
    }
  };
  auto sigpack = [&](const float* big) {
    #pragma unroll
    for (int j = 0; j < 2; ++j) {
      float bgv = big[(nt0 + j)*16 + l15];
      #pragma unroll
      for (int mt = 0; mt < 4; ++mt) {
        sig[mt][j][0].h[0] = (_Float16)sigmoidf_(acc[mt][j][0] + bgv);
        sig[mt][j][0].h[1] = (_Float16)sigmoidf_(acc[mt][j][1] + bgv);
        sig[mt][j][1].h[0] = (_Float16)sigmoidf_(acc[mt][j][2] + bgv);
        sig[mt][j][1].h[1] = (_Float16)sigmoidf_(acc[mt][j][3] + bgv);
      }
    }
  };
  // drain wave's bounce tile to global: 4-lane groups write full 64B lines
  auto bounce_out = [&](_Float16* dst) {
    asm volatile("s_waitcnt lgkmcnt(0)" ::: "memory");
    const int q2 = lane & 3, cl = lane >> 2;     // cl 0..15
    #pragma unroll
    for (int i = 0; i < 4; ++i) {
      int cp  = cl + (i >> 1) * 16;              // c' 0..31
      int ofs = (i & 1) * 32 + q2 * 8;           // row start (fp16 units)
      uint4 v = *(const uint4*)&bnc[w][cp * 72 + ofs];
      *(uint4*)(dst + (size_t)(w*32 + cp) * RR + r0 + ofs) = v;
    }
  };
  auto combine_store = [&](const float* bia, _Float16* dst) {
    #pragma unroll
    for (int j = 0; j < 2; ++j) {
      int c = (nt0 + j)*16 + l15;
      float bav = bia[c];
      #pragma unroll
      for (int mt = 0; mt < 4; ++mt) {
        union { uint2 u2; _Float16 h[4]; } pk;
        pk.h[0] = (_Float16)((acc[mt][j][0] + bav) * (float)sig[mt][j][0].h[0]);
        pk.h[1] = (_Float16)((acc[mt][j][1] + bav) * (float)sig[mt][j][0].h[1]);
        pk.h[2] = (_Float16)((acc[mt][j][2] + bav) * (float)sig[mt][j][1].h[0]);
        pk.h[3] = (_Float16)((acc[mt][j][3] + bav) * (float)sig[mt][j][1].h[1]);
        *(uint2*)&bnc[w][(j*16 + l15) * 72 + mt*16 + quad*4] = pk.u2;
      }
    }
    bounce_out(dst);
  };

  // pair 1: Wga (gate) then Wa (proj) -> at
  loadw(1); dogemm(); sigpack(bga);
  loadw(0); dogemm();
  loadw(3);                          // prefetch Wgb
  combine_store(ba, at);
  // pair 2: Wgb then Wb -> bt
  dogemm(); sigpack(bgb);
  loadw(2); dogemm();
  loadw(4);                          // prefetch Wg
  combine_store(bb, bt);
  // gate: Wg
  dogemm();
  #pragma unroll
  for (int j = 0; j < 2; ++j) {
    float bgv = bg[(nt0 + j)*16 + l15];
    #pragma unroll
    for (int mt = 0; mt < 4; ++mt) {
      union { uint2 u2; _Float16 h[4]; } pk;
      #pragma unroll
      for (int r = 0; r < 4; ++r)
        pk.h[r] = (_Float16)sigmoidf_(acc[mt][j][r] + bgv);
      *(uint2*)&bnc[w][(j*16 + l15) * 72 + mt*16 + quad*4] = pk.u2;
    }
  }
  bounce_out(gate);
}

// ---------------------------------------------------------------------------
// k3: triangle einsum. Per channel c: o_t[c] = A_c(384x384) @ B_c^T.
// grid (9 tiles, 128 channels); block computes 128x128 o-tile, wave = 64x64.
// NEW: K-step 32, double-buffered LDS (stride 40 = conflict-free for the
// fragment read pattern), ONE barrier per K-step, two register staging sets
// (P/Q) so next-next tile's global loads are issued BEFORE compute.
// ---------------------------------------------------------------------------
__global__ __launch_bounds__(256, 3) void k3_tri(
    const _Float16* __restrict__ at, const _Float16* __restrict__ bt, _Float16* __restrict__ o)
{
  __shared__ __align__(16) _Float16 As[2][128 * 40];
  __shared__ __align__(16) _Float16 Bs[2][128 * 40];
  const int t = threadIdx.x;
  const int w = t >> 6, lane = t & 63, l15 = lane & 15, quad = lane >> 4;
  const int c = blockIdx.y;
  const int i0 = (blockIdx.x / 3) * 128, j0 = (blockIdx.x % 3) * 128;
  const int wi = w >> 1, wj = w & 1;
  const size_t base = (size_t)c * RR;
  const _Float16* A  = at + base;
  const _Float16* Bp = bt + base;

  // staging: row = t>>1 (0..127), chunk = (t&1)*16 fp16 (32B); 64B/row/step
  const int srow = t >> 1, sch = (t & 1) * 16;
  const _Float16* ga = A  + (size_t)(i0 + srow) * NN + sch;
  const _Float16* gb = Bp + (size_t)(j0 + srow) * NN + sch;
  _Float16* const pa0 = &As[0][srow * 40 + sch];
  _Float16* const pb0 = &Bs[0][srow * 40 + sch];
  _Float16* const pa1 = &As[1][srow * 40 + sch];
  _Float16* const pb1 = &Bs[1][srow * 40 + sch];

  floatx4 acc[4][4];
  #pragma unroll
  for (int mt = 0; mt < 4; ++mt)
    #pragma unroll
    for (int nt = 0; nt < 4; ++nt) acc[mt][nt] = zero4();

  f16x8 aP0,aP1,bP0,bP1, aQ0,aQ1,bQ0,bQ1;

  auto gloadP = [&](int kk) {
    aP0 = *(const f16x8*)(ga + kk); aP1 = *(const f16x8*)(ga + kk + 8);
    bP0 = *(const f16x8*)(gb + kk); bP1 = *(const f16x8*)(gb + kk + 8);
  };
  auto gloadQ = [&](int kk) {
    aQ0 = *(const f16x8*)(ga + kk); aQ1 = *(const f16x8*)(ga + kk + 8);
    bQ0 = *(const f16x8*)(gb + kk); bQ1 = *(const f16x8*)(gb + kk + 8);
  };
  auto swriteP = [&](int buf) {
    _Float16* pa = buf ? pa1 : pa0; _Float16* pb = buf ? pb1 : pb0;
    *(f16x8*)pa = aP0; *(f16x8*)(pa + 8) = aP1;
    *(f16x8*)pb = bP0; *(f16x8*)(pb + 8) = bP1;
  };
  auto swriteQ = [&](int buf) {
    _Float16* pa = buf ? pa1 : pa0; _Float16* pb = buf ? pb1 : pb0;
    *(f16x8*)pa = aQ0; *(f16x8*)(pa + 8) = aQ1;
    *(f16x8*)pb = bQ0; *(f16x8*)(pb + 8) = bQ1;
  };
  auto compute = [&](int buf) {
    f16x8 af[4], bfr[4];
    #pragma unroll
    for (int mt = 0; mt < 4; ++mt)
      af[mt] = *(const f16x8*)&As[buf][(wi*64 + mt*16 + l15) * 40 + quad*8];
    #pragma unroll
    for (int nt = 0; nt < 4; ++nt)
      bfr[nt] = *(const f16x8*)&Bs[buf][(wj*64 + nt*16 + l15) * 40 + quad*8];
    #pragma unroll
    for (int mt = 0; mt < 4; ++mt)
      #pragma unroll
      for (int nt = 0; nt < 4; ++nt)
        acc[mt][nt] = __builtin_amdgcn_mfma_f32_16x16x32_f16(af[mt], bfr[nt], acc[mt][nt], 0, 0, 0);
  };

  // 12 K-steps of 32. step s lives in buf[s&1].
  gloadP(0); swriteP(0); gloadP(32);
  __syncthreads();
  #pragma unroll
  for (int s = 0; s < 12; s += 2) {
    if (s + 2 < 12) gloadQ((s + 2) * 32);   // in flight during compute
    compute(0);
    swriteP(1);                              // step s+1 -> buf1
    __syncthreads();
    if (s + 3 < 12) gloadP((s + 3) * 32);
    compute(1);
    if (s + 2 < 12) { swriteQ(0); __syncthreads(); }
  }

  // store fp16, 256B contiguous per wave instruction (full lines)
  #pragma unroll
  for (int mt = 0; mt < 4; ++mt) {
    #pragma unroll
    for (int r = 0; r < 4; ++r) {
      int i = i0 + wi*64 + mt*16 + quad*4 + r;
      _Float16* orow = o + base + (size_t)i * NN + j0 + wj*64;
      #pragma unroll
      for (int nt = 0; nt < 4; ++nt) orow[nt*16 + l15] = (_Float16)acc[mt][nt][r];
    }
  }
}

// ---------------------------------------------------------------------------
// k4: per 64-position tile: gather o16 (channel-major fp16) -> LDS transpose
//     -> LN2 IN PLACE -> N-split MFMA with Wo from L2 -> *gate -> fp32 out.
// (unchanged this round)
// ---------------------------------------------------------------------------
__global__ __launch_bounds__(256, 4) void k4_out(
    const _Float16* __restrict__ o, const _Float16* __restrict__ gate,
    const float* __restrict__ ln2g, const float* __restrict__ ln2b,
    const _Float16* __restrict__ wo5, const float* __restrict__ bo,
    float* __restrict__ out)
{
  __shared__ __align__(16) _Float16 osb[64][136];   // o tile [pos][c]; LN2 in place
  const int t = threadIdx.x;
  const int w = t >> 6, lane = t & 63, l15 = lane & 15, quad = lane >> 4;
  const int r0 = blockIdx.x * 64;
  const int nt0 = w * 2;

  // gather o16: 16B per lane per channel plane, transpose into [pos][c]
  #pragma unroll
  for (int it = 0; it < 4; ++it) {
    int f = (it * 256 + t) * 8;
    int cx = f >> 6, p = f & 63;
    f16x8 v = *(const f16x8*)(o + (size_t)cx * RR + r0 + p);
    #pragma unroll
    for (int i = 0; i < 8; ++i) osb[p + i][cx] = v[i];
  }
  __syncthreads();

  // LN2 in place: lane (g = lane>>4, h = lane&15) owns cols h*8..h*8+7
  {
    const int g = lane >> 4, h = lane & 15;
    float4 ga = *(const float4*)(ln2g + h*8);
    float4 gb = *(const float4*)(ln2g + h*8 + 4);
    float4 bba = *(const float4*)(ln2b + h*8);
    float4 bbb = *(const float4*)(ln2b + h*8 + 4);
    #pragma unroll
    for (int rr = 0; rr < 4; ++rr) {
      int row = w * 16 + rr * 4 + g;
      f16x8 xv = *(const f16x8*)&osb[row][h*8];
      float x0 = (float)xv[0], x1 = (float)xv[1], x2 = (float)xv[2], x3 = (float)xv[3];
      float x4 = (float)xv[4], x5 = (float)xv[5], x6 = (float)xv[6], x7 = (float)xv[7];
      float s = x0+x1+x2+x3+x4+x5+x6+x7;
      float q = x0*x0+x1*x1+x2*x2+x3*x3+x4*x4+x5*x5+x6*x6+x7*x7;
      #pragma unroll
      for (int m = 1; m < 16; m <<= 1) { s += __shfl_xor(s, m); q += __shfl_xor(q, m); }
      float mean = s * (1.f/128.f);
      float var  = q * (1.f/128.f) - mean*mean;
      float rs = rsqrtf(var + 1e-5f);
      union { uint4 u; _Float16 hh[8]; } pk;
      pk.hh[0] = (_Float16)((x0 - mean) * rs * ga.x + bba.x);
      pk.hh[1] = (_Float16)((x1 - mean) * rs * ga.y + bba.y);
      pk.hh[2] = (_Float16)((x2 - mean) * rs * ga.z + bba.z);
      pk.hh[3] = (_Float16)((x3 - mean) * rs * ga.w + bba.w);
      pk.hh[4] = (_Float16)((x4 - mean) * rs * gb.x + bbb.x);
      pk.hh[5] = (_Float16)((x5 - mean) * rs * gb.y + bbb.y);
      pk.hh[6] = (_Float16)((x6 - mean) * rs * gb.z + bbb.z);
      pk.hh[7] = (_Float16)((x7 - mean) * rs * gb.w + bbb.w);
      *(uint4*)&osb[row][h * 8] = pk.u;
    }
  }
  __syncthreads();

  // N-split GEMM: wave owns channel-tiles {2w,2w+1}; Wo streamed from L2
  f16x8 bw[4][2];
  {
    const _Float16* p = wo5 + lane * 8;
    #pragma unroll
    for (int k0 = 0; k0 < 4; ++k0)
      #pragma unroll
      for (int j = 0; j < 2; ++j)
        bw[k0][j] = *(const f16x8*)(p + (k0*8 + nt0 + j) * 512);
  }
  floatx4 acc[4][2];
  #pragma unroll
  for (int mt = 0; mt < 4; ++mt) {
    acc[mt][0] = zero4(); acc[mt][1] = zero4();
    #pragma unroll
    for (int k0 = 0; k0 < 4; ++k0) {
      f16x8 af = *(const f16x8*)&osb[mt*16 + l15][k0*32 + quad*8];
      acc[mt][0] = __builtin_amdgcn_mfma_f32_16x16x32_f16(af, bw[k0][0], acc[mt][0], 0, 0, 0);
      acc[mt][1] = __builtin_amdgcn_mfma_f32_16x16x32_f16(af, bw[k0][1], acc[mt][1], 0, 0, 0);
    }
  }

  // epilogue: out = gate * (acc + bo); gate channel-major fp16, 8B loads
  #pragma unroll
  for (int j = 0; j < 2; ++j) {
    int cch = (nt0 + j)*16 + l15;
    float bov = bo[cch];
    #pragma unroll
    for (int mt = 0; mt < 4; ++mt) {
      union { uint2 u2; _Float16 h[4]; } gk;
      gk.u2 = *(const uint2*)(gate + (size_t)cch * RR + r0 + mt*16 + quad*4);
      #pragma unroll
      for (int r = 0; r < 4; ++r) {
        int rl = mt*16 + quad*4 + r;
        out[(size_t)(r0 + rl) * NC + cch] = (float)gk.h[r] * (acc[mt][j][r] + bov);
      }
    }
  }
}

// ---------------------------------------------------------------------------
// Workspace layout (bytes):
//   a_t   @ 0          : 147456*128*2 = 37748736   (fp16, channel-major)
//   b_t   @ 37748736   : 37748736
//   gate  @ 75497472   : 37748736                  (fp16, channel-major)
//   o16   @ 113246208  : 147456*128*2 = 37748736   (fp16, channel-major)
//   wf    @ 188743680  : 6*16384*2 = 196608        (fragment-major fp16 weights)
//   total 188940288
// ---------------------------------------------------------------------------
extern "C" void kernel_launch(void* const* d_in, const int* in_sizes, int n_in,
                              void* d_out, int out_size, void* d_ws, size_t ws_size,
                              hipStream_t stream) {
  const float* z    = (const float*)d_in[0];
  const float* l1g  = (const float*)d_in[1];
  const float* l1b  = (const float*)d_in[2];
  const float* l2g  = (const float*)d_in[3];
  const float* l2b  = (const float*)d_in[4];
  const float* Wa   = (const float*)d_in[5];
  const float* ba   = (const float*)d_in[6];
  const float* Wga  = (const float*)d_in[7];
  const float* bga  = (const float*)d_in[8];
  const float* Wb   = (const float*)d_in[9];
  const float* bb   = (const float*)d_in[10];
  const float* Wgb  = (const float*)d_in[11];
  const float* bgb  = (const float*)d_in[12];
  const float* Wg   = (const float*)d_in[13];
  const float* bg   = (const float*)d_in[14];
  const float* Wo   = (const float*)d_in[15];
  const float* bo   = (const float*)d_in[16];

  char* ws = (char*)d_ws;
  _Float16* at_  = (_Float16*)(ws + 0);
  _Float16* bt_  = (_Float16*)(ws + 37748736);
  _Float16* gate = (_Float16*)(ws + 75497472);
  _Float16* o16  = (_Float16*)(ws + 113246208);
  _Float16* wf   = (_Float16*)(ws + 188743680);

  hipLaunchKernelGGL(k0_wt, dim3(6), dim3(256), 0, stream, Wa, Wga, Wb, Wgb, Wg, Wo, wf);
  hipLaunchKernelGGL(k2_ln_gemm, dim3(2304), dim3(256), 0, stream,
                     z, l1g, l1b, wf, ba, bga, bb, bgb, bg, at_, bt_, gate);
  hipLaunchKernelGGL(k3_tri, dim3(9, 128), dim3(256), 0, stream, at_, bt_, o16);
  hipLaunchKernelGGL(k4_out, dim3(2304), dim3(256), 0, stream,
                     o16, gate, l2g, l2b, wf + 5*16384, bo, (float*)d_out);
}

// Round 8
// 323.183 us; speedup vs baseline: 1.0383x; 1.0182x over previous
//
#include <hip/hip_runtime.h>
#include <stdint.h>

typedef _Float16 f16x8 __attribute__((ext_vector_type(8)));
typedef float floatx4 __attribute__((ext_vector_type(4)));

#define RR 147456   // 384*384 rows
#define NC 128      // channels
#define NN 384
// chunk-interleaved layout for at/bt/gate/o16:
//   addr(pos, c) = (pos>>6)*8192 + c*64 + (pos&63)   [fp16 units]
// one chunk = 64 positions x 128 channels = 16KB, matches the 64-row tiles
// of k2/k4 exactly -> fully contiguous per-block streams.

__device__ inline floatx4 zero4() { floatx4 v; v[0]=0.f; v[1]=0.f; v[2]=0.f; v[3]=0.f; return v; }
__device__ inline float sigmoidf_(float x) { return 1.f / (1.f + __expf(-x)); }

// ---------------------------------------------------------------------------
// k0: repack six fp32 128x128 weights into fp16 FRAGMENT-MAJOR order:
//   wf[slot][ ((k0*8 + nt)*64 + lane)*8 + j ] = W[k][n]
//   where k = k0*32 + (lane>>4)*8 + j,  n = nt*16 + (lane&15)
// A lane's MFMA B-operand for (k0,nt) is ONE coalesced 16B load.
// slots: 0=Wa 1=Wga 2=Wb 3=Wgb 4=Wg 5=Wo. L2-resident afterwards.
// ---------------------------------------------------------------------------
__global__ __launch_bounds__(256) void k0_wt(
    const float* __restrict__ w0, const float* __restrict__ w1,
    const float* __restrict__ w2, const float* __restrict__ w3,
    const float* __restrict__ w4, const float* __restrict__ w5,
    _Float16* __restrict__ wf)
{
  const float* w;
  switch (blockIdx.x) {
    case 0: w = w0; break; case 1: w = w1; break; case 2: w = w2; break;
    case 3: w = w3; break; case 4: w = w4; break; default: w = w5; break;
  }
  _Float16* out = wf + blockIdx.x * 16384;
  const int t = threadIdx.x;
  for (int it = 0; it < 64; ++it) {
    int f = it * 256 + t;
    int j  = f & 7;
    int ln = (f >> 3) & 63;
    int nt = (f >> 9) & 7;
    int k0 = f >> 12;
    int k = k0 * 32 + (ln >> 4) * 8 + j;
    int n = nt * 16 + (ln & 15);
    out[f] = (_Float16)w[k * 128 + n];
  }
}

// ---------------------------------------------------------------------------
// k2: per 64-row tile (= one chunk): LN1 -> zn fp16 in LDS -> ONE barrier ->
// 5 GEMMs (N-split: wave w owns channel-tiles {2w,2w+1}; register-lean).
// Outputs bounce through per-wave LDS then drain as ONE contiguous 16KB
// chunk per output (1KB per wave-instruction) -> no HBM granule scatter.
// ---------------------------------------------------------------------------
__global__ __launch_bounds__(256, 4) void k2_ln_gemm(
    const float* __restrict__ z, const float* __restrict__ ln1g, const float* __restrict__ ln1b,
    const _Float16* __restrict__ wf,
    const float* __restrict__ ba, const float* __restrict__ bga,
    const float* __restrict__ bb, const float* __restrict__ bgb,
    const float* __restrict__ bg,
    _Float16* __restrict__ at, _Float16* __restrict__ bt, _Float16* __restrict__ gate)
{
  __shared__ __align__(16) _Float16 zns[64][136];    // zn tile, padded stride
  __shared__ __align__(16) _Float16 bnc[4][32 * 72]; // per-wave store bounce [c'][row], stride 72
  const int t = threadIdx.x;
  const int w = t >> 6, lane = t & 63;
  const int l15 = lane & 15, quad = lane >> 4;
  const int r0 = blockIdx.x * 64;
  const int nt0 = w * 2;            // this wave's channel-tile pair

  // ---- LN1: wave w owns rows w*16..w*16+15 (16-lane-group reduce)
  {
    const int g = lane >> 4, h = lane & 15;
    float4 ga = *(const float4*)(ln1g + h*8);
    float4 gb = *(const float4*)(ln1g + h*8 + 4);
    float4 bba = *(const float4*)(ln1b + h*8);
    float4 bbb = *(const float4*)(ln1b + h*8 + 4);
    #pragma unroll
    for (int rr = 0; rr < 4; ++rr) {
      int row = w * 16 + rr * 4 + g;
      const float* zp = z + (size_t)(r0 + row) * NC + h * 8;
      float4 xa = *(const float4*)zp;
      float4 xb = *(const float4*)(zp + 4);
      float s = xa.x + xa.y + xa.z + xa.w + xb.x + xb.y + xb.z + xb.w;
      float q = xa.x*xa.x + xa.y*xa.y + xa.z*xa.z + xa.w*xa.w
              + xb.x*xb.x + xb.y*xb.y + xb.z*xb.z + xb.w*xb.w;
      #pragma unroll
      for (int m = 1; m < 16; m <<= 1) { s += __shfl_xor(s, m); q += __shfl_xor(q, m); }
      float mean = s * (1.f/128.f);
      float var  = q * (1.f/128.f) - mean*mean;
      float rs = rsqrtf(var + 1e-5f);
      union { uint4 u; _Float16 hh[8]; } pk;
      pk.hh[0] = (_Float16)((xa.x - mean) * rs * ga.x + bba.x);
      pk.hh[1] = (_Float16)((xa.y - mean) * rs * ga.y + bba.y);
      pk.hh[2] = (_Float16)((xa.z - mean) * rs * ga.z + bba.z);
      pk.hh[3] = (_Float16)((xa.w - mean) * rs * ga.w + bba.w);
      pk.hh[4] = (_Float16)((xb.x - mean) * rs * gb.x + bbb.x);
      pk.hh[5] = (_Float16)((xb.y - mean) * rs * gb.y + bbb.y);
      pk.hh[6] = (_Float16)((xb.z - mean) * rs * gb.z + bbb.z);
      pk.hh[7] = (_Float16)((xb.w - mean) * rs * gb.w + bbb.w);
      *(uint4*)&zns[row][h * 8] = pk.u;
    }
  }
  __syncthreads();

  const _Float16* pw = wf + lane * 8;
  f16x8 bw[4][2];                   // single weight buffer
  floatx4 acc[4][2];                // single accumulator set
  union PkU { unsigned int u; _Float16 h[2]; };
  PkU sig[4][2][2];                 // packed sigmoid results

  auto loadw = [&](int slot) {
    const _Float16* p = pw + slot * 16384;
    #pragma unroll
    for (int k0 = 0; k0 < 4; ++k0)
      #pragma unroll
      for (int j = 0; j < 2; ++j)
        bw[k0][j] = *(const f16x8*)(p + (k0*8 + nt0 + j) * 512);
  };
  auto dogemm = [&]() {
    #pragma unroll
    for (int mt = 0; mt < 4; ++mt) {
      acc[mt][0] = zero4(); acc[mt][1] = zero4();
      #pragma unroll
      for (int k0 = 0; k0 < 4; ++k0) {
        f16x8 af = *(const f16x8*)&zns[mt*16 + l15][k0*32 + quad*8];
        acc[mt][0] = __builtin_amdgcn_mfma_f32_16x16x32_f16(af, bw[k0][0], acc[mt][0], 0, 0, 0);
        acc[mt][1] = __builtin_amdgcn_mfma_f32_16x16x32_f16(af, bw[k0][1], acc[mt][1], 0, 0, 0);
      }
    }
  };
  auto sigpack = [&](const float* big) {
    #pragma unroll
    for (int j = 0; j < 2; ++j) {
      float bgv = big[(nt0 + j)*16 + l15];
      #pragma unroll
      for (int mt = 0; mt < 4; ++mt) {
        sig[mt][j][0].h[0] = (_Float16)sigmoidf_(acc[mt][j][0] + bgv);
        sig[mt][j][0].h[1] = (_Float16)sigmoidf_(acc[mt][j][1] + bgv);
        sig[mt][j][1].h[0] = (_Float16)sigmoidf_(acc[mt][j][2] + bgv);
        sig[mt][j][1].h[1] = (_Float16)sigmoidf_(acc[mt][j][3] + bgv);
      }
    }
  };
  // drain wave's bounce tile: wave writes channels w*32..w*32+31 of this
  // block's chunk = 4KB contiguous (1KB per instruction); block = 16KB.
  auto bounce_out = [&](_Float16* dst) {
    asm volatile("s_waitcnt lgkmcnt(0)" ::: "memory");
    _Float16* base = dst + (size_t)blockIdx.x * 8192 + w * 2048;
    #pragma unroll
    for (int i = 0; i < 4; ++i) {
      int f = i * 512 + lane * 8;          // f = cp*64 + pos
      int cp = f >> 6, pos = f & 63;
      uint4 v = *(const uint4*)&bnc[w][cp * 72 + pos];
      *(uint4*)(base + f) = v;
    }
  };
  auto combine_store = [&](const float* bia, _Float16* dst) {
    #pragma unroll
    for (int j = 0; j < 2; ++j) {
      int c = (nt0 + j)*16 + l15;
      float bav = bia[c];
      #pragma unroll
      for (int mt = 0; mt < 4; ++mt) {
        union { uint2 u2; _Float16 h[4]; } pk;
        pk.h[0] = (_Float16)((acc[mt][j][0] + bav) * (float)sig[mt][j][0].h[0]);
        pk.h[1] = (_Float16)((acc[mt][j][1] + bav) * (float)sig[mt][j][0].h[1]);
        pk.h[2] = (_Float16)((acc[mt][j][2] + bav) * (float)sig[mt][j][1].h[0]);
        pk.h[3] = (_Float16)((acc[mt][j][3] + bav) * (float)sig[mt][j][1].h[1]);
        *(uint2*)&bnc[w][(j*16 + l15) * 72 + mt*16 + quad*4] = pk.u2;
      }
    }
    bounce_out(dst);
  };

  // pair 1: Wga (gate) then Wa (proj) -> at
  loadw(1); dogemm(); sigpack(bga);
  loadw(0); dogemm();
  loadw(3);                          // prefetch Wgb
  combine_store(ba, at);
  // pair 2: Wgb then Wb -> bt
  dogemm(); sigpack(bgb);
  loadw(2); dogemm();
  loadw(4);                          // prefetch Wg
  combine_store(bb, bt);
  // gate: Wg
  dogemm();
  #pragma unroll
  for (int j = 0; j < 2; ++j) {
    float bgv = bg[(nt0 + j)*16 + l15];
    #pragma unroll
    for (int mt = 0; mt < 4; ++mt) {
      union { uint2 u2; _Float16 h[4]; } pk;
      #pragma unroll
      for (int r = 0; r < 4; ++r)
        pk.h[r] = (_Float16)sigmoidf_(acc[mt][j][r] + bgv);
      *(uint2*)&bnc[w][(j*16 + l15) * 72 + mt*16 + quad*4] = pk.u2;
    }
  }
  bounce_out(gate);
}

// ---------------------------------------------------------------------------
// k3: triangle einsum. Per channel c: o_t[c] = A_c(384x384) @ B_c^T.
// grid (9 tiles, 128 channels); block computes 128x128 o-tile, wave = 64x64.
// K-step 32, double-buffered LDS (stride 40), ONE barrier per K-step,
// two register staging sets (P/Q). Reads/writes use the chunk layout:
// adjacent-c blocks (consecutive blockIdx.y) touch adjacent 128B segments
// of the same 16KB chunk -> L2/L3 line sharing + full-chunk write coverage.
// ---------------------------------------------------------------------------
__global__ __launch_bounds__(256, 3) void k3_tri(
    const _Float16* __restrict__ at, const _Float16* __restrict__ bt, _Float16* __restrict__ o)
{
  __shared__ __align__(16) _Float16 As[2][128 * 40];
  __shared__ __align__(16) _Float16 Bs[2][128 * 40];
  const int t = threadIdx.x;
  const int w = t >> 6, lane = t & 63, l15 = lane & 15, quad = lane >> 4;
  const int c = blockIdx.y;
  const int i0 = (blockIdx.x / 3) * 128, j0 = (blockIdx.x % 3) * 128;
  const int wi = w >> 1, wj = w & 1;

  // staging: row = t>>1 (0..127), chunk-half = (t&1)*16 fp16 (32B)
  const int srow = t >> 1, sch = (t & 1) * 16;
  const _Float16* gaRow = at + (size_t)(i0 + srow) * 6 * 8192 + (size_t)c * 64;
  const _Float16* gbRow = bt + (size_t)(j0 + srow) * 6 * 8192 + (size_t)c * 64;
  _Float16* const pa0 = &As[0][srow * 40 + sch];
  _Float16* const pb0 = &Bs[0][srow * 40 + sch];
  _Float16* const pa1 = &As[1][srow * 40 + sch];
  _Float16* const pb1 = &Bs[1][srow * 40 + sch];

  floatx4 acc[4][4];
  #pragma unroll
  for (int mt = 0; mt < 4; ++mt)
    #pragma unroll
    for (int nt = 0; nt < 4; ++nt) acc[mt][nt] = zero4();

  f16x8 aP0,aP1,bP0,bP1, aQ0,aQ1,bQ0,bQ1;

  auto gofs = [&](int kk) -> size_t {
    int x = kk + sch;                       // within-row k offset
    return (size_t)(x >> 6) * 8192 + (size_t)(x & 63);
  };
  auto gloadP = [&](int kk) {
    size_t go = gofs(kk);
    aP0 = *(const f16x8*)(gaRow + go); aP1 = *(const f16x8*)(gaRow + go + 8);
    bP0 = *(const f16x8*)(gbRow + go); bP1 = *(const f16x8*)(gbRow + go + 8);
  };
  auto gloadQ = [&](int kk) {
    size_t go = gofs(kk);
    aQ0 = *(const f16x8*)(gaRow + go); aQ1 = *(const f16x8*)(gaRow + go + 8);
    bQ0 = *(const f16x8*)(gbRow + go); bQ1 = *(const f16x8*)(gbRow + go + 8);
  };
  auto swriteP = [&](int buf) {
    _Float16* pa = buf ? pa1 : pa0; _Float16* pb = buf ? pb1 : pb0;
    *(f16x8*)pa = aP0; *(f16x8*)(pa + 8) = aP1;
    *(f16x8*)pb = bP0; *(f16x8*)(pb + 8) = bP1;
  };
  auto swriteQ = [&](int buf) {
    _Float16* pa = buf ? pa1 : pa0; _Float16* pb = buf ? pb1 : pb0;
    *(f16x8*)pa = aQ0; *(f16x8*)(pa + 8) = aQ1;
    *(f16x8*)pb = bQ0; *(f16x8*)(pb + 8) = bQ1;
  };
  auto compute = [&](int buf) {
    f16x8 af[4], bfr[4];
    #pragma unroll
    for (int mt = 0; mt < 4; ++mt)
      af[mt] = *(const f16x8*)&As[buf][(wi*64 + mt*16 + l15) * 40 + quad*8];
    #pragma unroll
    for (int nt = 0; nt < 4; ++nt)
      bfr[nt] = *(const f16x8*)&Bs[buf][(wj*64 + nt*16 + l15) * 40 + quad*8];
    #pragma unroll
    for (int mt = 0; mt < 4; ++mt)
      #pragma unroll
      for (int nt = 0; nt < 4; ++nt)
        acc[mt][nt] = __builtin_amdgcn_mfma_f32_16x16x32_f16(af[mt], bfr[nt], acc[mt][nt], 0, 0, 0);
  };

  // 12 K-steps of 32. step s lives in buf[s&1].
  gloadP(0); swriteP(0); gloadP(32);
  __syncthreads();
  #pragma unroll
  for (int s = 0; s < 12; s += 2) {
    if (s + 2 < 12) gloadQ((s + 2) * 32);   // in flight during compute
    compute(0);
    swriteP(1);                              // step s+1 -> buf1
    __syncthreads();
    if (s + 3 < 12) gloadP((s + 3) * 32);
    compute(1);
    if (s + 2 < 12) { swriteQ(0); __syncthreads(); }
  }

  // store o16 in chunk layout: per (i, wave) a full 128B [c][64] segment,
  // adjacent-c blocks complete the chunk.
  #pragma unroll
  for (int mt = 0; mt < 4; ++mt) {
    #pragma unroll
    for (int r = 0; r < 4; ++r) {
      int i = i0 + wi*64 + mt*16 + quad*4 + r;
      _Float16* obase = o + (size_t)(i*6 + (j0 >> 6) + wj) * 8192 + (size_t)c * 64;
      #pragma unroll
      for (int nt = 0; nt < 4; ++nt) obase[nt*16 + l15] = (_Float16)acc[mt][nt][r];
    }
  }
}

// ---------------------------------------------------------------------------
// k4: per 64-position tile (= one chunk): gather o16 (16KB contiguous) ->
// LDS transpose -> LN2 IN PLACE -> N-split MFMA with Wo from L2 -> *gate
// (16KB contiguous chunk read) -> fp32 out.
// ---------------------------------------------------------------------------
__global__ __launch_bounds__(256, 4) void k4_out(
    const _Float16* __restrict__ o, const _Float16* __restrict__ gate,
    const float* __restrict__ ln2g, const float* __restrict__ ln2b,
    const _Float16* __restrict__ wo5, const float* __restrict__ bo,
    float* __restrict__ out)
{
  __shared__ __align__(16) _Float16 osb[64][136];   // o tile [pos][c]; LN2 in place
  const int t = threadIdx.x;
  const int w = t >> 6, lane = t & 63, l15 = lane & 15, quad = lane >> 4;
  const int r0 = blockIdx.x * 64;
  const int nt0 = w * 2;

  // gather o16 chunk: fully contiguous 16KB, transpose into [pos][c]
  {
    const _Float16* ob = o + (size_t)blockIdx.x * 8192;
    #pragma unroll
    for (int it = 0; it < 4; ++it) {
      int f = (it * 256 + t) * 8;
      int cx = f >> 6, p = f & 63;
      f16x8 v = *(const f16x8*)(ob + f);
      #pragma unroll
      for (int i = 0; i < 8; ++i) osb[p + i][cx] = v[i];
    }
  }
  __syncthreads();

  // LN2 in place: lane (g = lane>>4, h = lane&15) owns cols h*8..h*8+7
  {
    const int g = lane >> 4, h = lane & 15;
    float4 ga = *(const float4*)(ln2g + h*8);
    float4 gb = *(const float4*)(ln2g + h*8 + 4);
    float4 bba = *(const float4*)(ln2b + h*8);
    float4 bbb = *(const float4*)(ln2b + h*8 + 4);
    #pragma unroll
    for (int rr = 0; rr < 4; ++rr) {
      int row = w * 16 + rr * 4 + g;
      f16x8 xv = *(const f16x8*)&osb[row][h*8];
      float x0 = (float)xv[0], x1 = (float)xv[1], x2 = (float)xv[2], x3 = (float)xv[3];
      float x4 = (float)xv[4], x5 = (float)xv[5], x6 = (float)xv[6], x7 = (float)xv[7];
      float s = x0+x1+x2+x3+x4+x5+x6+x7;
      float q = x0*x0+x1*x1+x2*x2+x3*x3+x4*x4+x5*x5+x6*x6+x7*x7;
      #pragma unroll
      for (int m = 1; m < 16; m <<= 1) { s += __shfl_xor(s, m); q += __shfl_xor(q, m); }
      float mean = s * (1.f/128.f);
      float var  = q * (1.f/128.f) - mean*mean;
      float rs = rsqrtf(var + 1e-5f);
      union { uint4 u; _Float16 hh[8]; } pk;
      pk.hh[0] = (_Float16)((x0 - mean) * rs * ga.x + bba.x);
      pk.hh[1] = (_Float16)((x1 - mean) * rs * ga.y + bba.y);
      pk.hh[2] = (_Float16)((x2 - mean) * rs * ga.z + bba.z);
      pk.hh[3] = (_Float16)((x3 - mean) * rs * ga.w + bba.w);
      pk.hh[4] = (_Float16)((x4 - mean) * rs * gb.x + bbb.x);
      pk.hh[5] = (_Float16)((x5 - mean) * rs * gb.y + bbb.y);
      pk.hh[6] = (_Float16)((x6 - mean) * rs * gb.z + bbb.z);
      pk.hh[7] = (_Float16)((x7 - mean) * rs * gb.w + bbb.w);
      *(uint4*)&osb[row][h * 8] = pk.u;
    }
  }
  __syncthreads();

  // N-split GEMM: wave owns channel-tiles {2w,2w+1}; Wo streamed from L2
  f16x8 bw[4][2];
  {
    const _Float16* p = wo5 + lane * 8;
    #pragma unroll
    for (int k0 = 0; k0 < 4; ++k0)
      #pragma unroll
      for (int j = 0; j < 2; ++j)
        bw[k0][j] = *(const f16x8*)(p + (k0*8 + nt0 + j) * 512);
  }
  floatx4 acc[4][2];
  #pragma unroll
  for (int mt = 0; mt < 4; ++mt) {
    acc[mt][0] = zero4(); acc[mt][1] = zero4();
    #pragma unroll
    for (int k0 = 0; k0 < 4; ++k0) {
      f16x8 af = *(const f16x8*)&osb[mt*16 + l15][k0*32 + quad*8];
      acc[mt][0] = __builtin_amdgcn_mfma_f32_16x16x32_f16(af, bw[k0][0], acc[mt][0], 0, 0, 0);
      acc[mt][1] = __builtin_amdgcn_mfma_f32_16x16x32_f16(af, bw[k0][1], acc[mt][1], 0, 0, 0);
    }
  }

  // epilogue: out = gate * (acc + bo); gate chunk-layout, 8B loads
  #pragma unroll
  for (int j = 0; j < 2; ++j) {
    int cch = (nt0 + j)*16 + l15;
    float bov = bo[cch];
    #pragma unroll
    for (int mt = 0; mt < 4; ++mt) {
      union { uint2 u2; _Float16 h[4]; } gk;
      gk.u2 = *(const uint2*)(gate + (size_t)blockIdx.x * 8192 + (size_t)cch * 64 + mt*16 + quad*4);
      #pragma unroll
      for (int r = 0; r < 4; ++r) {
        int rl = mt*16 + quad*4 + r;
        out[(size_t)(r0 + rl) * NC + cch] = (float)gk.h[r] * (acc[mt][j][r] + bov);
      }
    }
  }
}

// ---------------------------------------------------------------------------
// Workspace layout (bytes):
//   a_t   @ 0          : 2304 chunks * 16KB = 37748736   (fp16, chunk layout)
//   b_t   @ 37748736   : 37748736
//   gate  @ 75497472   : 37748736                        (fp16, chunk layout)
//   o16   @ 113246208  : 37748736                        (fp16, chunk layout)
//   wf    @ 188743680  : 6*16384*2 = 196608              (fragment-major fp16 weights)
//   total 188940288
// ---------------------------------------------------------------------------
extern "C" void kernel_launch(void* const* d_in, const int* in_sizes, int n_in,
                              void* d_out, int out_size, void* d_ws, size_t ws_size,
                              hipStream_t stream) {
  const float* z    = (const float*)d_in[0];
  const float* l1g  = (const float*)d_in[1];
  const float* l1b  = (const float*)d_in[2];
  const float* l2g  = (const float*)d_in[3];
  const float* l2b  = (const float*)d_in[4];
  const float* Wa   = (const float*)d_in[5];
  const float* ba   = (const float*)d_in[6];
  const float* Wga  = (const float*)d_in[7];
  const float* bga  = (const float*)d_in[8];
  const float* Wb   = (const float*)d_in[9];
  const float* bb   = (const float*)d_in[10];
  const float* Wgb  = (const float*)d_in[11];
  const float* bgb  = (const float*)d_in[12];
  const float* Wg   = (const float*)d_in[13];
  const float* bg   = (const float*)d_in[14];
  const float* Wo   = (const float*)d_in[15];
  const float* bo   = (const float*)d_in[16];

  char* ws = (char*)d_ws;
  _Float16* at_  = (_Float16*)(ws + 0);
  _Float16* bt_  = (_Float16*)(ws + 37748736);
  _Float16* gate = (_Float16*)(ws + 75497472);
  _Float16* o16  = (_Float16*)(ws + 113246208);
  _Float16* wf   = (_Float16*)(ws + 188743680);

  hipLaunchKernelGGL(k0_wt, dim3(6), dim3(256), 0, stream, Wa, Wga, Wb, Wgb, Wg, Wo, wf);
  hipLaunchKernelGGL(k2_ln_gemm, dim3(2304), dim3(256), 0, stream,
                     z, l1g, l1b, wf, ba, bga, bb, bgb, bg, at_, bt_, gate);
  hipLaunchKernelGGL(k3_tri, dim3(9, 128), dim3(256), 0, stream, at_, bt_, o16);
  hipLaunchKernelGGL(k4_out, dim3(2304), dim3(256), 0, stream,
                     o16, gate, l2g, l2b, wf + 5*16384, bo, (float*)d_out);
}